// Round 6
// baseline (514.266 us; speedup 1.0000x reference)
//
#include <hip/hip_runtime.h>

#define HW    16384   // 128*128
#define NCH   256     // C
#define NB    16      // batch
#define INTER 128
#define HW4   4096    // HW/4 (float4 units)
#define WSTR  34      // wsum row stride (32 lane-partials + pad)
#define NT    16      // spatial tiles per image (256 float4 each)

// Output: [16, 4, 128, 128] f32.
//   out[b,0]    = gelu_exact(sum_c x[b,c,:,:] * W3[c])
//   out[b,1..3] = x[b, top3_ch_r, :, :]
// psum[b] (16*256 f32) borrows d_out's channel-1 slot between kernels A and B.

// ---------------------------------------------------------------------------
// Kernel A: fused pool + x3 pass over x (268 MB).
// grid (16 tiles, 16 b), 512 threads; each wave owns 32 channels over a
// 256-float4 tile (4 q-iters/channel). TRIPLE-buffered 8-float4 batches
// (2 channels each, 16 batches): at step i, issue batch i+2 and process
// batch i -> consumed data was issued 2 PROCESS bodies (~800+ cy) earlier,
// sustained in-flight = 16 loads/thread = 128 KB/CU (R3 double-buffer
// consumed same-iteration data every 2nd batch and stalled on vmcnt).
// 1 shfl + 1 ds_write per channel; distributed epilogue (256 threads finish
// one pixel each). launch_bounds(512,2): 256-VGPR headroom, NO forced
// occupancy (R4: forcing 4/SIMD clamped to 64 VGPR and spilled 200 MB).
// ---------------------------------------------------------------------------
__global__ __launch_bounds__(512, 2) void k_pool_x3(
    const float* __restrict__ x, const float* __restrict__ W3, float* out)
{
    const int tile = blockIdx.x;           // 0..15
    const int b    = blockIdx.y;
    const int tid  = threadIdx.x;
    const int wave = tid >> 6, lane = tid & 63;
    const int c0   = wave << 5;            // this wave's first channel

    __shared__ float  w3f[NCH];            // 1 KB
    __shared__ float  wsum[NCH * WSTR];    // 34 KB: [channel][32 lane-partials]
    __shared__ float4 comb[8][256];        // 32 KB: per-wave x3 partials

    if (tid < NCH) w3f[tid] = W3[tid];
    __syncthreads();

    // base: batch b, channel c0, float4-position tile*256 + lane
    const float4* xb = (const float4*)x + (size_t)b * NCH * HW4
                     + (size_t)c0 * HW4 + tile * 256 + lane;

    float4 a[4];                           // x3 partial per q-iter
    #pragma unroll
    for (int q = 0; q < 4; ++q) a[q] = make_float4(0.f, 0.f, 0.f, 0.f);

    float4 R0[8], R1[8], R2[8];            // 3 x (2 channels x 4 q-iters)

    // batch BT = channels {2*BT, 2*BT+1}; element j = h*4 + q
    #define LOAD(R, BT)                                                     \
        _Pragma("unroll")                                                   \
        for (int j = 0; j < 8; ++j)                                         \
            R[j] = xb[(size_t)((BT) * 2 + (j >> 2)) * HW4 + (j & 3) * 64];

    #define PROC(R, BT)                                                     \
        _Pragma("unroll")                                                   \
        for (int h = 0; h < 2; ++h) {                                       \
            const int c = (BT) * 2 + h;                                     \
            const float w = w3f[c0 + c];                                    \
            float cs = 0.f;                                                 \
            _Pragma("unroll")                                               \
            for (int q = 0; q < 4; ++q) {                                   \
                float4 v = R[h * 4 + q];                                    \
                a[q].x = fmaf(v.x, w, a[q].x);                              \
                a[q].y = fmaf(v.y, w, a[q].y);                              \
                a[q].z = fmaf(v.z, w, a[q].z);                              \
                a[q].w = fmaf(v.w, w, a[q].w);                              \
                cs += (v.x + v.y) + (v.z + v.w);                            \
            }                                                               \
            cs += __shfl_xor(cs, 32);                                       \
            if (lane < 32) wsum[(c0 + c) * WSTR + lane] = cs;               \
        }

    // STEP i: issue batch i+2 into the buffer freed at step i-1, process i.
    #define STEP(I, RP, RL)                                                 \
        { if ((I) + 2 < 16) { LOAD(RL, (I) + 2) } PROC(RP, I) }

    LOAD(R0, 0)
    LOAD(R1, 1)
    STEP( 0, R0, R2)  STEP( 1, R1, R0)  STEP( 2, R2, R1)
    STEP( 3, R0, R2)  STEP( 4, R1, R0)  STEP( 5, R2, R1)
    STEP( 6, R0, R2)  STEP( 7, R1, R0)  STEP( 8, R2, R1)
    STEP( 9, R0, R2)  STEP(10, R1, R0)  STEP(11, R2, R1)
    STEP(12, R0, R2)  STEP(13, R1, R0)  STEP(14, R2, R1)
    STEP(15, R0, R2)
    #undef STEP
    #undef PROC
    #undef LOAD

    // dump x3 partials; ONE barrier covers wsum + comb
    #pragma unroll
    for (int q = 0; q < 4; ++q) comb[wave][q * 64 + lane] = a[q];
    __syncthreads();

    // pool reduce: 2 threads per channel, 16 lane-partials each
    {
        const int ch = tid >> 1, half = tid & 1;
        const float* rowp = &wsum[ch * WSTR + half * 16];
        float s = 0.f;
        #pragma unroll
        for (int k = 0; k < 8; ++k) {
            float2 v2 = *(const float2*)(rowp + k * 2);
            s += v2.x + v2.y;
        }
        s += __shfl_xor(s, 1);
        if (half == 0)
            out[(size_t)(b * 4 + 1) * HW + tile * NCH + ch] = s;  // psum slot
    }

    // x3 finale: 256 threads, one pixel each
    if (tid < 256) {
        float4 v = comb[0][tid];
        #pragma unroll
        for (int j = 1; j < 8; ++j) {
            float4 u = comb[j][tid];
            v.x += u.x; v.y += u.y; v.z += u.z; v.w += u.w;
        }
        const float is2 = 0.70710678118654752440f;
        float4 r;
        r.x = 0.5f * v.x * (1.f + erff(v.x * is2));
        r.y = 0.5f * v.y * (1.f + erff(v.y * is2));
        r.z = 0.5f * v.z * (1.f + erff(v.z * is2));
        r.w = 0.5f * v.w * (1.f + erff(v.w * is2));
        ((float4*)out)[(size_t)b * 4 * HW4 + tile * 256 + tid] = r;
    }
}

// ---------------------------------------------------------------------------
// Kernel B: per-sample tiny MLP chain: p -> g/theta/phi -> f -> y -> wy
// 16 blocks (one per b), 256 threads.
// ---------------------------------------------------------------------------
__global__ __launch_bounds__(256) void k_mlp(
    const float* outbuf,
    const float* __restrict__ Wg, const float* __restrict__ bg,
    const float* __restrict__ Wt, const float* __restrict__ bt,
    const float* __restrict__ Wp, const float* __restrict__ bp,
    const float* __restrict__ Wf, const float* __restrict__ bfv,
    const float* __restrict__ Wz, const float* __restrict__ bz,
    float* __restrict__ p_out, float* __restrict__ wy_out)
{
    const int b = blockIdx.x, tid = threadIdx.x;
    __shared__ float sp[NCH];
    __shared__ float sg[INTER], sth[INTER], sph[INTER];
    __shared__ float red[NCH];
    __shared__ float sy[INTER];
    __shared__ float sf;

    const float* psum = outbuf + (size_t)(b * 4 + 1) * HW;
    float s = 0.f;
    #pragma unroll
    for (int t = 0; t < NT; ++t) s += psum[t * NCH + tid];
    float pv = s * (1.0f / 16384.0f);
    sp[tid] = pv;
    p_out[b * NCH + tid] = pv;
    __syncthreads();

    for (int j = tid; j < 3 * INTER; j += 256) {
        const float* Wrow; float bias; int i, which;
        if (j < INTER)        { i = j;           Wrow = Wg + i * NCH; bias = bg[i]; which = 0; }
        else if (j < 2*INTER) { i = j - INTER;   Wrow = Wt + i * NCH; bias = bt[i]; which = 1; }
        else                  { i = j - 2*INTER; Wrow = Wp + i * NCH; bias = bp[i]; which = 2; }
        float acc = bias;
        for (int k = 0; k < NCH; k += 4) {
            float4 q = *(const float4*)(Wrow + k);
            acc = fmaf(q.x, sp[k+0], acc);
            acc = fmaf(q.y, sp[k+1], acc);
            acc = fmaf(q.z, sp[k+2], acc);
            acc = fmaf(q.w, sp[k+3], acc);
        }
        if (which == 0) sg[i] = acc;
        else if (which == 1) sth[i] = acc;
        else sph[i] = acc;
    }
    __syncthreads();

    float cat = (tid < INTER) ? sth[tid] : sph[tid - INTER];
    red[tid] = cat * Wf[tid];
    __syncthreads();
    if (tid == 0) {
        float acc = bfv[0];
        for (int k = 0; k < NCH; ++k) acc += red[k];
        sf = fmaxf(acc, 0.f);
    }
    __syncthreads();
    if (tid < INTER) sy[tid] = sf * sg[tid];
    __syncthreads();

    {
        const float* Wrow = Wz + tid * INTER;
        float acc = bz[tid];
        for (int k = 0; k < INTER; k += 4) {
            float4 q = *(const float4*)(Wrow + k);
            acc = fmaf(q.x, sy[k+0], acc);
            acc = fmaf(q.y, sy[k+1], acc);
            acc = fmaf(q.z, sy[k+2], acc);
            acc = fmaf(q.w, sy[k+3], acc);
        }
        wy_out[b * NCH + tid] = acc;
    }
}

// ---------------------------------------------------------------------------
// Kernel C: BatchNorm (batch stats) + residual + sigmoid + top-3 selection.
// 16 blocks (one per b), 256 threads. Writes sel[b][3] to ws; NO gather here.
// ---------------------------------------------------------------------------
__global__ __launch_bounds__(256) void k_bn_topk(
    const float* __restrict__ wy, const float* __restrict__ p,
    const float* __restrict__ gamma, const float* __restrict__ beta,
    int* __restrict__ sel_out)
{
    const int b = blockIdx.x, tid = threadIdx.x;
    const int wave = tid >> 6, lane = tid & 63;
    __shared__ float wsc[4];
    __shared__ int   wid[4];
    __shared__ int   sel[3];

    float vv[16];
    float mu = 0.f;
    #pragma unroll
    for (int bb = 0; bb < 16; ++bb) { vv[bb] = wy[bb * NCH + tid]; mu += vv[bb]; }
    mu *= (1.f / 16.f);
    float var = 0.f;
    #pragma unroll
    for (int bb = 0; bb < 16; ++bb) { float d = vv[bb] - mu; var = fmaf(d, d, var); }
    var *= (1.f / 16.f);

    float bn = gamma[tid] * (vv[b] - mu) * rsqrtf(var + 1e-5f) + beta[tid];
    float z  = bn + p[b * NCH + tid];
    float sc = 1.f / (1.f + expf(-z));

    for (int r = 0; r < 3; ++r) {
        float s = sc; int id = tid;
        #pragma unroll
        for (int m = 1; m <= 32; m <<= 1) {
            float so = __shfl_xor(s, m);
            int   io = __shfl_xor(id, m);
            if (so > s || (so == s && io < id)) { s = so; id = io; }
        }
        if (lane == 0) { wsc[wave] = s; wid[wave] = id; }
        __syncthreads();
        if (tid == 0) {
            float bs = wsc[0]; int bi = wid[0];
            for (int w = 1; w < 4; ++w)
                if (wsc[w] > bs || (wsc[w] == bs && wid[w] < bi)) { bs = wsc[w]; bi = wid[w]; }
            sel[r] = bi;
        }
        __syncthreads();
        if (tid == sel[r]) sc = -1e30f;
        __syncthreads();
    }
    if (tid < 3) sel_out[b * 3 + tid] = sel[tid];
}

// ---------------------------------------------------------------------------
// Kernel D: gather top-3 channels, spread over 192 blocks (4 seg x 3 r x 16 b)
// 16 KB copied per block, float4, bit-exact.
// ---------------------------------------------------------------------------
__global__ __launch_bounds__(256) void k_gather(
    const float* __restrict__ x, const int* __restrict__ sel,
    float* __restrict__ out)
{
    const int seg = blockIdx.x;   // 4
    const int r   = blockIdx.y;   // 3
    const int b   = blockIdx.z;   // 16
    const int ch  = sel[b * 3 + r];
    const float4* src = (const float4*)x + (size_t)(b * NCH + ch) * HW4 + seg * 1024;
    float4*       dst = (float4*)out + (size_t)(b * 4 + 1 + r) * HW4 + seg * 1024;
    #pragma unroll
    for (int i = 0; i < 4; ++i)
        dst[i * 256 + threadIdx.x] = src[i * 256 + threadIdx.x];
}

extern "C" void kernel_launch(void* const* d_in, const int* in_sizes, int n_in,
                              void* d_out, int out_size, void* d_ws, size_t ws_size,
                              hipStream_t stream)
{
    const float* x     = (const float*)d_in[0];
    const float* Wg    = (const float*)d_in[1];
    const float* bg    = (const float*)d_in[2];
    const float* Wt    = (const float*)d_in[3];
    const float* bt    = (const float*)d_in[4];
    const float* Wp    = (const float*)d_in[5];
    const float* bp    = (const float*)d_in[6];
    const float* Wf    = (const float*)d_in[7];
    const float* bfv   = (const float*)d_in[8];
    const float* Wz    = (const float*)d_in[9];
    const float* bz    = (const float*)d_in[10];
    const float* gamma = (const float*)d_in[11];
    const float* beta  = (const float*)d_in[12];
    const float* W3    = (const float*)d_in[13];
    float* out = (float*)d_out;

    // d_ws: wy[16][256] f32 | p[16][256] f32 | sel[16][3] int
    float* wy  = (float*)d_ws;
    float* p   = wy + NB * NCH;
    int*   sel = (int*)(p + NB * NCH);

    k_pool_x3<<<dim3(NT, 16), 512, 0, stream>>>(x, W3, out);
    k_mlp<<<NB, 256, 0, stream>>>(out, Wg, bg, Wt, bt, Wp, bp, Wf, bfv, Wz, bz, p, wy);
    k_bn_topk<<<NB, 256, 0, stream>>>(wy, p, gamma, beta, sel);
    k_gather<<<dim3(4, 3, NB), 256, 0, stream>>>(x, sel, out);
}

// Round 7
// 409.623 us; speedup vs baseline: 1.2555x; 1.2555x over previous
//
#include <hip/hip_runtime.h>

#define HW    16384   // 128*128
#define NCH   256     // C
#define NB    16      // batch
#define INTER 128
#define HW4   4096    // HW/4 (float4 units)
#define WS2   33      // wsum row stride (32 lane-partials + pad)
#define NT    32      // spatial tiles per image (128 float4 each)

// Output: [16, 4, 128, 128] f32.
//   out[b,0]    = gelu_exact(sum_c x[b,c,:,:] * W3[c])
//   out[b,1..3] = x[b, top3_ch_r, :, :]
// psum[b] (32*256 f32) borrows d_out's channel-1 slot between kernels A and B.

// ---------------------------------------------------------------------------
// Kernel A: fused pool + x3 pass over x (268 MB).
// grid (32 tiles, 16 b) = 512 blocks x 256 threads -> 2 INDEPENDENT blocks
// per CU (42 KB LDS each, VGPR <= 128 via launch_bounds(256,2); R6 showed
// the (512,2)=128-VGPR cap spills a 3-buffer pipeline, so keep the proven
// 8+8 double-buffer = 64 buffer VGPRs). One block's main loop covers the
// other's barriers + epilogue (untested R4 hypothesis, now without spill).
// Each of 4 waves owns 64 channels over a 128-float4 tile (2 q-iters);
// 8 pixels/channel accumulate in registers, then 1 shfl + 1 ds_write per
// channel. Distributed epilogue: 1 thread/channel pool reduce, 128 threads
// finish one x3 pixel each.
// ---------------------------------------------------------------------------
__global__ __launch_bounds__(256, 2) void k_pool_x3(
    const float* __restrict__ x, const float* __restrict__ W3, float* out)
{
    const int tile = blockIdx.x;           // 0..31
    const int b    = blockIdx.y;
    const int tid  = threadIdx.x;
    const int wave = tid >> 6, lane = tid & 63;
    const int c0   = wave << 6;            // this wave's first channel (64 each)

    __shared__ float  w3f[NCH];            // 1 KB
    __shared__ float  wsum[NCH * WS2];     // 33 KB: [channel][32 lane-partials]
    __shared__ float4 comb[4][128];        // 8 KB: per-wave x3 partials

    w3f[tid] = W3[tid];
    __syncthreads();

    // base: batch b, channel c0, float4-position tile*128 + lane
    const float4* xb = (const float4*)x + (size_t)b * NCH * HW4
                     + (size_t)c0 * HW4 + tile * 128 + lane;

    float4 a0 = make_float4(0.f, 0.f, 0.f, 0.f);   // pixel lane
    float4 a1 = make_float4(0.f, 0.f, 0.f, 0.f);   // pixel 64+lane

    float4 bufA[8], bufB[8];               // 4 channels x 2 q-iters each

    // batch BT = local channels {4*BT .. 4*BT+3}; element j = h*2 + q
    #define LOAD(R, BT)                                                     \
        _Pragma("unroll")                                                   \
        for (int j = 0; j < 8; ++j)                                         \
            R[j] = xb[(size_t)((BT) * 4 + (j >> 1)) * HW4 + (j & 1) * 64];

    #define PROC(R, BT)                                                     \
        _Pragma("unroll")                                                   \
        for (int h = 0; h < 4; ++h) {                                       \
            const int c = (BT) * 4 + h;                                     \
            const float w = w3f[c0 + c];                                    \
            float4 v0 = R[h * 2], v1 = R[h * 2 + 1];                        \
            a0.x = fmaf(v0.x, w, a0.x); a0.y = fmaf(v0.y, w, a0.y);         \
            a0.z = fmaf(v0.z, w, a0.z); a0.w = fmaf(v0.w, w, a0.w);         \
            a1.x = fmaf(v1.x, w, a1.x); a1.y = fmaf(v1.y, w, a1.y);         \
            a1.z = fmaf(v1.z, w, a1.z); a1.w = fmaf(v1.w, w, a1.w);         \
            float cs = ((v0.x + v0.y) + (v0.z + v0.w))                      \
                     + ((v1.x + v1.y) + (v1.z + v1.w));                     \
            cs += __shfl_xor(cs, 32);                                       \
            if (lane < 32) wsum[(c0 + c) * WS2 + lane] = cs;                \
        }

    LOAD(bufA, 0)
    for (int bt = 0; bt < 16; bt += 2) {
        LOAD(bufB, bt + 1)
        PROC(bufA, bt)
        if (bt + 2 < 16) { LOAD(bufA, bt + 2) }
        PROC(bufB, bt + 1)
    }
    #undef PROC
    #undef LOAD

    // dump x3 partials; ONE barrier covers wsum + comb
    comb[wave][lane]      = a0;
    comb[wave][64 + lane] = a1;
    __syncthreads();

    // pool reduce: 1 thread per channel, 32 lane-partials each
    {
        const float* rowp = &wsum[tid * WS2];
        float s = 0.f;
        #pragma unroll
        for (int k = 0; k < 16; ++k) {
            float2 v2 = *(const float2*)(rowp + k * 2);
            s += v2.x + v2.y;
        }
        out[(size_t)(b * 4 + 1) * HW + tile * NCH + tid] = s;  // psum slot
    }

    // x3 finale: 128 threads, one pixel each
    if (tid < 128) {
        float4 v = comb[0][tid];
        #pragma unroll
        for (int j = 1; j < 4; ++j) {
            float4 u = comb[j][tid];
            v.x += u.x; v.y += u.y; v.z += u.z; v.w += u.w;
        }
        const float is2 = 0.70710678118654752440f;
        float4 r;
        r.x = 0.5f * v.x * (1.f + erff(v.x * is2));
        r.y = 0.5f * v.y * (1.f + erff(v.y * is2));
        r.z = 0.5f * v.z * (1.f + erff(v.z * is2));
        r.w = 0.5f * v.w * (1.f + erff(v.w * is2));
        ((float4*)out)[(size_t)b * 4 * HW4 + tile * 128 + tid] = r;
    }
}

// ---------------------------------------------------------------------------
// Kernel B: per-sample tiny MLP chain: p -> g/theta/phi -> f -> y -> wy
// 16 blocks (one per b), 256 threads.
// ---------------------------------------------------------------------------
__global__ __launch_bounds__(256) void k_mlp(
    const float* outbuf,
    const float* __restrict__ Wg, const float* __restrict__ bg,
    const float* __restrict__ Wt, const float* __restrict__ bt,
    const float* __restrict__ Wp, const float* __restrict__ bp,
    const float* __restrict__ Wf, const float* __restrict__ bfv,
    const float* __restrict__ Wz, const float* __restrict__ bz,
    float* __restrict__ p_out, float* __restrict__ wy_out)
{
    const int b = blockIdx.x, tid = threadIdx.x;
    __shared__ float sp[NCH];
    __shared__ float sg[INTER], sth[INTER], sph[INTER];
    __shared__ float red[NCH];
    __shared__ float sy[INTER];
    __shared__ float sf;

    const float* psum = outbuf + (size_t)(b * 4 + 1) * HW;
    float s = 0.f;
    #pragma unroll
    for (int t = 0; t < NT; ++t) s += psum[t * NCH + tid];
    float pv = s * (1.0f / 16384.0f);
    sp[tid] = pv;
    p_out[b * NCH + tid] = pv;
    __syncthreads();

    for (int j = tid; j < 3 * INTER; j += 256) {
        const float* Wrow; float bias; int i, which;
        if (j < INTER)        { i = j;           Wrow = Wg + i * NCH; bias = bg[i]; which = 0; }
        else if (j < 2*INTER) { i = j - INTER;   Wrow = Wt + i * NCH; bias = bt[i]; which = 1; }
        else                  { i = j - 2*INTER; Wrow = Wp + i * NCH; bias = bp[i]; which = 2; }
        float acc = bias;
        for (int k = 0; k < NCH; k += 4) {
            float4 q = *(const float4*)(Wrow + k);
            acc = fmaf(q.x, sp[k+0], acc);
            acc = fmaf(q.y, sp[k+1], acc);
            acc = fmaf(q.z, sp[k+2], acc);
            acc = fmaf(q.w, sp[k+3], acc);
        }
        if (which == 0) sg[i] = acc;
        else if (which == 1) sth[i] = acc;
        else sph[i] = acc;
    }
    __syncthreads();

    float cat = (tid < INTER) ? sth[tid] : sph[tid - INTER];
    red[tid] = cat * Wf[tid];
    __syncthreads();
    if (tid == 0) {
        float acc = bfv[0];
        for (int k = 0; k < NCH; ++k) acc += red[k];
        sf = fmaxf(acc, 0.f);
    }
    __syncthreads();
    if (tid < INTER) sy[tid] = sf * sg[tid];
    __syncthreads();

    {
        const float* Wrow = Wz + tid * INTER;
        float acc = bz[tid];
        for (int k = 0; k < INTER; k += 4) {
            float4 q = *(const float4*)(Wrow + k);
            acc = fmaf(q.x, sy[k+0], acc);
            acc = fmaf(q.y, sy[k+1], acc);
            acc = fmaf(q.z, sy[k+2], acc);
            acc = fmaf(q.w, sy[k+3], acc);
        }
        wy_out[b * NCH + tid] = acc;
    }
}

// ---------------------------------------------------------------------------
// Kernel C: BatchNorm (batch stats) + residual + sigmoid + top-3 selection.
// 16 blocks (one per b), 256 threads. Writes sel[b][3] to ws; NO gather here.
// ---------------------------------------------------------------------------
__global__ __launch_bounds__(256) void k_bn_topk(
    const float* __restrict__ wy, const float* __restrict__ p,
    const float* __restrict__ gamma, const float* __restrict__ beta,
    int* __restrict__ sel_out)
{
    const int b = blockIdx.x, tid = threadIdx.x;
    const int wave = tid >> 6, lane = tid & 63;
    __shared__ float wsc[4];
    __shared__ int   wid[4];
    __shared__ int   sel[3];

    float vv[16];
    float mu = 0.f;
    #pragma unroll
    for (int bb = 0; bb < 16; ++bb) { vv[bb] = wy[bb * NCH + tid]; mu += vv[bb]; }
    mu *= (1.f / 16.f);
    float var = 0.f;
    #pragma unroll
    for (int bb = 0; bb < 16; ++bb) { float d = vv[bb] - mu; var = fmaf(d, d, var); }
    var *= (1.f / 16.f);

    float bn = gamma[tid] * (vv[b] - mu) * rsqrtf(var + 1e-5f) + beta[tid];
    float z  = bn + p[b * NCH + tid];
    float sc = 1.f / (1.f + expf(-z));

    for (int r = 0; r < 3; ++r) {
        float s = sc; int id = tid;
        #pragma unroll
        for (int m = 1; m <= 32; m <<= 1) {
            float so = __shfl_xor(s, m);
            int   io = __shfl_xor(id, m);
            if (so > s || (so == s && io < id)) { s = so; id = io; }
        }
        if (lane == 0) { wsc[wave] = s; wid[wave] = id; }
        __syncthreads();
        if (tid == 0) {
            float bs = wsc[0]; int bi = wid[0];
            for (int w = 1; w < 4; ++w)
                if (wsc[w] > bs || (wsc[w] == bs && wid[w] < bi)) { bs = wsc[w]; bi = wid[w]; }
            sel[r] = bi;
        }
        __syncthreads();
        if (tid == sel[r]) sc = -1e30f;
        __syncthreads();
    }
    if (tid < 3) sel_out[b * 3 + tid] = sel[tid];
}

// ---------------------------------------------------------------------------
// Kernel D: gather top-3 channels, spread over 192 blocks (4 seg x 3 r x 16 b)
// 16 KB copied per block, float4, bit-exact.
// ---------------------------------------------------------------------------
__global__ __launch_bounds__(256) void k_gather(
    const float* __restrict__ x, const int* __restrict__ sel,
    float* __restrict__ out)
{
    const int seg = blockIdx.x;   // 4
    const int r   = blockIdx.y;   // 3
    const int b   = blockIdx.z;   // 16
    const int ch  = sel[b * 3 + r];
    const float4* src = (const float4*)x + (size_t)(b * NCH + ch) * HW4 + seg * 1024;
    float4*       dst = (float4*)out + (size_t)(b * 4 + 1 + r) * HW4 + seg * 1024;
    #pragma unroll
    for (int i = 0; i < 4; ++i)
        dst[i * 256 + threadIdx.x] = src[i * 256 + threadIdx.x];
}

extern "C" void kernel_launch(void* const* d_in, const int* in_sizes, int n_in,
                              void* d_out, int out_size, void* d_ws, size_t ws_size,
                              hipStream_t stream)
{
    const float* x     = (const float*)d_in[0];
    const float* Wg    = (const float*)d_in[1];
    const float* bg    = (const float*)d_in[2];
    const float* Wt    = (const float*)d_in[3];
    const float* bt    = (const float*)d_in[4];
    const float* Wp    = (const float*)d_in[5];
    const float* bp    = (const float*)d_in[6];
    const float* Wf    = (const float*)d_in[7];
    const float* bfv   = (const float*)d_in[8];
    const float* Wz    = (const float*)d_in[9];
    const float* bz    = (const float*)d_in[10];
    const float* gamma = (const float*)d_in[11];
    const float* beta  = (const float*)d_in[12];
    const float* W3    = (const float*)d_in[13];
    float* out = (float*)d_out;

    // d_ws: wy[16][256] f32 | p[16][256] f32 | sel[16][3] int
    float* wy  = (float*)d_ws;
    float* p   = wy + NB * NCH;
    int*   sel = (int*)(p + NB * NCH);

    k_pool_x3<<<dim3(NT, 16), 256, 0, stream>>>(x, W3, out);
    k_mlp<<<NB, 256, 0, stream>>>(out, Wg, bg, Wt, bt, Wp, bp, Wf, bfv, Wz, bz, p, wy);
    k_bn_topk<<<NB, 256, 0, stream>>>(wy, p, gamma, beta, sel);
    k_gather<<<dim3(4, 3, NB), 256, 0, stream>>>(x, sel, out);
}